// Round 1
// baseline (2118.604 us; speedup 1.0000x reference)
//
#include <hip/hip_runtime.h>
#include <hip/hip_bf16.h>

// Problem constants
#define C1c 256
#define C2c 256
#define NBAT 16
#define HH 56
#define WW 56
#define KS 13
#define PADc 6
#define HP 68                    // 56 + 2*6
#define NPIX (NBAT*HH*WW)        // 50176
#define PIXTILES (NPIX/128)      // 392

typedef __bf16 bf16;
typedef bf16 bf16x8 __attribute__((ext_vector_type(8)));
typedef float floatx4 __attribute__((ext_vector_type(4)));

// Workspace layout (bf16):
//   xT : [NBAT*HP*HP][C1]      = 18,939,904 elems (37,879,808 B)
//   wT : [169*8][256][32]      = 11,075,584 elems (22,151,168 B)
#define XT_ELEMS ((size_t)NBAT*HP*HP*C1c)
#define WT_ELEMS ((size_t)169*8*256*32)

// ---------------------------------------------------------------------------
// Pre-pass 1: x (N,C,H,W) fp32 -> xT [(n*68+hp)*68+wp][c1] bf16, zero-padded
// ---------------------------------------------------------------------------
__global__ __launch_bounds__(256) void xform_x(const float* __restrict__ x,
                                               bf16* __restrict__ xT) {
  int j = blockIdx.x * 256 + threadIdx.x;   // NBAT*HP*HP*32 threads
  int pos = j >> 5;
  int c1 = (j & 31) * 8;
  int n = pos / (HP * HP);
  int r = pos - n * (HP * HP);
  int hp = r / HP;
  int wp = r - hp * HP;
  int ih = hp - PADc, iw = wp - PADc;
  bf16x8 v;
  if (ih >= 0 && ih < HH && iw >= 0 && iw < WW) {
    const float* xp = x + ((size_t)(n * C1c + c1) * HH + ih) * WW + iw;
#pragma unroll
    for (int i = 0; i < 8; i++) v[i] = (bf16)xp[(size_t)i * HH * WW];
  } else {
#pragma unroll
    for (int i = 0; i < 8; i++) v[i] = (bf16)0.f;
  }
  *(bf16x8*)(xT + (size_t)pos * C1c + c1) = v;
}

// ---------------------------------------------------------------------------
// Pre-pass 2: w (C2,C1,13,13) fp32 -> wT [khkw*8+q][c2][32] bf16
// ---------------------------------------------------------------------------
__global__ __launch_bounds__(256) void xform_w(const float* __restrict__ w,
                                               bf16* __restrict__ wT) {
  int j = blockIdx.x * 256 + threadIdx.x;   // 169*8*256*4 threads
  int part = j & 3;
  int c2 = (j >> 2) & 255;
  int qk = j >> 10;            // khkw*8 + q, 0..1351
  int q = qk & 7;
  int khkw = qk >> 3;
  int c1 = q * 32 + part * 8;
  const float* wp = w + ((size_t)c2 * C1c + c1) * (KS * KS) + khkw;
  bf16x8 v;
#pragma unroll
  for (int i = 0; i < 8; i++) v[i] = (bf16)wp[(size_t)i * KS * KS];
  *(bf16x8*)(wT + (size_t)j * 8) = v;
}

// ---------------------------------------------------------------------------
// Main: implicit-GEMM conv + BN + SiLU
//   tile: 128 c2 x 128 pixels, BK=32, 4 waves of 64x64 (4x4 mfma 16x16x32)
// ---------------------------------------------------------------------------
__device__ __forceinline__ void gload_lds16(const bf16* g, bf16* l) {
  __builtin_amdgcn_global_load_lds(
      (const __attribute__((address_space(1))) void*)(g),
      (__attribute__((address_space(3))) void*)(l),
      16, 0, 0);
}

__global__ __launch_bounds__(256, 2) void conv_mfma(
    const bf16* __restrict__ xT, const bf16* __restrict__ wT,
    const float* __restrict__ gamma, const float* __restrict__ beta,
    const float* __restrict__ rmean, const float* __restrict__ rvar,
    float* __restrict__ out) {
  __shared__ __attribute__((aligned(16))) bf16 As[128 * 32];
  __shared__ __attribute__((aligned(16))) bf16 Bs[128 * 32];
  __shared__ float sS[128];
  __shared__ float sB[128];

  const int tid = threadIdx.x;
  const int lane = tid & 63;
  const int wave = tid >> 6;           // 0..3
  const int wm = wave >> 1, wn = wave & 1;

  const int bid = blockIdx.x;
  const int c2t = bid & 1;             // 0..1
  const int pixt = bid >> 1;           // 0..391
  const int c2base = c2t * 128;
  const int pixbase = pixt * 128;

  // BN scale/bias for this block's 128 c2 rows
  if (tid < 128) {
    int row = c2base + tid;
    float s = gamma[row] * rsqrtf(rvar[row] + 1e-5f);
    sS[tid] = s;
    sB[tid] = beta[row] - rmean[row] * s;
  }

  // --- staging lane constants ---
  const int part = lane & 3;           // 16B sub-chunk within a 64B row
  const int rsub = lane >> 2;          // row within a 16-row issue

  // A: wave covers c2 rows [wave*32, wave*32+32) in 2 issues of 16 rows
  const bf16* aPtr = wT + (size_t)(c2base + wave * 32 + rsub) * 32 + part * 8;

  // B: wave covers pixels [wave*32, wave*32+32) in 2 issues of 16 pixels
  size_t pOff0, pOff1;
  {
#pragma unroll
    for (int i = 0; i < 2; i++) {
      int pix = pixbase + wave * 32 + i * 16 + rsub;
      int n = pix / (HH * WW);
      int rr = pix - n * (HH * WW);
      int oh = rr / WW;
      int ow = rr - oh * WW;
      size_t po = ((size_t)(n * HP + oh) * HP + ow) * C1c + part * 8;
      if (i == 0) pOff0 = po; else pOff1 = po;
    }
  }

  bf16* AsW = As + wave * 1024;        // wave*32 rows * 32 elems
  bf16* BsW = Bs + wave * 1024;

  // fragment-read lane constants
  const int mrow = lane & 15;
  const int kq = lane >> 4;            // k sub-block (8 elems each)

  floatx4 acc[4][4];
#pragma unroll
  for (int mi = 0; mi < 4; mi++)
#pragma unroll
    for (int ni = 0; ni < 4; ni++) acc[mi][ni] = (floatx4){0.f, 0.f, 0.f, 0.f};

  const bf16* aIter = aPtr;
  for (int kh = 0; kh < KS; kh++) {
    for (int kw = 0; kw < KS; kw++) {
      const int khw = (kh * HP + kw) * C1c;
      for (int q = 0; q < 8; q++) {
        const int bo = khw + q * 32;
        __syncthreads();   // previous iter's LDS reads done
        gload_lds16(aIter, AsW);
        gload_lds16(aIter + 512, AsW + 512);
        gload_lds16(xT + pOff0 + bo, BsW);
        gload_lds16(xT + pOff1 + bo, BsW + 512);
        asm volatile("s_waitcnt vmcnt(0)" ::: "memory");
        __syncthreads();   // staged tiles visible

        bf16x8 af[4], bfr[4];
#pragma unroll
        for (int mi = 0; mi < 4; mi++)
          af[mi] = *(const bf16x8*)(As + (wm * 64 + mi * 16 + mrow) * 32 + kq * 8);
#pragma unroll
        for (int ni = 0; ni < 4; ni++)
          bfr[ni] = *(const bf16x8*)(Bs + (wn * 64 + ni * 16 + mrow) * 32 + kq * 8);
#pragma unroll
        for (int mi = 0; mi < 4; mi++)
#pragma unroll
          for (int ni = 0; ni < 4; ni++)
            acc[mi][ni] = __builtin_amdgcn_mfma_f32_16x16x32_bf16(
                af[mi], bfr[ni], acc[mi][ni], 0, 0, 0);

        aIter += 8192;     // next K-chunk of wT (contiguous layout)
      }
    }
  }

  // --- epilogue: BN + SiLU, fp32 NCHW stores ---
  const int colL = lane & 15;
  const int quad = lane >> 4;
#pragma unroll
  for (int ni = 0; ni < 4; ni++) {
    int pix = pixbase + wn * 64 + ni * 16 + colL;
    int n = pix / (HH * WW);
    int rr = pix - n * (HH * WW);
    int oh = rr / WW;
    int ow = rr - oh * WW;
    size_t obase = (size_t)n * C2c * (HH * WW) + (size_t)oh * WW + ow;
#pragma unroll
    for (int mi = 0; mi < 4; mi++) {
      int row0 = wm * 64 + mi * 16 + quad * 4;
#pragma unroll
      for (int r = 0; r < 4; r++) {
        int rowl = row0 + r;
        float v = acc[mi][ni][r];
        v = v * sS[rowl] + sB[rowl];
        float o = v / (1.f + __expf(-v));
        out[obase + (size_t)(c2base + rowl) * (HH * WW)] = o;
      }
    }
  }
}

// ---------------------------------------------------------------------------
extern "C" void kernel_launch(void* const* d_in, const int* in_sizes, int n_in,
                              void* d_out, int out_size, void* d_ws, size_t ws_size,
                              hipStream_t stream) {
  const float* x     = (const float*)d_in[0];
  const float* w     = (const float*)d_in[1];
  const float* gamma = (const float*)d_in[2];
  const float* beta  = (const float*)d_in[3];
  const float* rmean = (const float*)d_in[4];
  const float* rvar  = (const float*)d_in[5];
  float* out = (float*)d_out;

  bf16* xT = (bf16*)d_ws;
  bf16* wT = xT + XT_ELEMS;

  if (ws_size < (XT_ELEMS + WT_ELEMS) * sizeof(bf16)) return;  // need ~57.3 MiB

  xform_x<<<(NBAT * HP * HP * 32) / 256, 256, 0, stream>>>(x, xT);
  xform_w<<<(169 * 8 * 256 * 4) / 256, 256, 0, stream>>>(w, wT);
  conv_mfma<<<2 * PIXTILES, 256, 0, stream>>>(xT, wT, gamma, beta, rmean, rvar, out);
}

// Round 2
// 1953.331 us; speedup vs baseline: 1.0846x; 1.0846x over previous
//
#include <hip/hip_runtime.h>
#include <hip/hip_bf16.h>

// Problem constants
#define C1c 256
#define C2c 256
#define NBAT 16
#define HH 56
#define WW 56
#define KS 13
#define PADc 6
#define HP 68                    // 56 + 2*6
#define NPIX (NBAT*HH*WW)        // 50176
#define PIXTILES (NPIX/128)      // 392
#define KSTEPS (169*4)           // 676 steps of BK=64

typedef __bf16 bf16;
typedef bf16 bf16x8 __attribute__((ext_vector_type(8)));
typedef float floatx4 __attribute__((ext_vector_type(4)));

// Workspace layout (bf16):
//   xT : [NBAT*HP*HP][C1]          = 18,939,904 elems (37,879,808 B)
//   wT : [676][256][64]            = 11,075,584 elems (22,151,168 B)
#define XT_ELEMS ((size_t)NBAT*HP*HP*C1c)
#define WT_ELEMS ((size_t)KSTEPS*256*64)

// ---------------------------------------------------------------------------
// Pre-pass 1: x (N,C,H,W) fp32 -> xT [(n*68+hp)*68+wp][c1] bf16, zero-padded
// ---------------------------------------------------------------------------
__global__ __launch_bounds__(256) void xform_x(const float* __restrict__ x,
                                               bf16* __restrict__ xT) {
  int j = blockIdx.x * 256 + threadIdx.x;   // NBAT*HP*HP*32 threads
  int pos = j >> 5;
  int c1 = (j & 31) * 8;
  int n = pos / (HP * HP);
  int r = pos - n * (HP * HP);
  int hp = r / HP;
  int wp = r - hp * HP;
  int ih = hp - PADc, iw = wp - PADc;
  bf16x8 v;
  if (ih >= 0 && ih < HH && iw >= 0 && iw < WW) {
    const float* xp = x + ((size_t)(n * C1c + c1) * HH + ih) * WW + iw;
#pragma unroll
    for (int i = 0; i < 8; i++) v[i] = (bf16)xp[(size_t)i * HH * WW];
  } else {
#pragma unroll
    for (int i = 0; i < 8; i++) v[i] = (bf16)0.f;
  }
  *(bf16x8*)(xT + (size_t)pos * C1c + c1) = v;
}

// ---------------------------------------------------------------------------
// Pre-pass 2: w (C2,C1,13,13) fp32 -> wT [kk][c2][64] bf16
//   kk = khkw*4 + q2,  c1 = q2*64 + t
// ---------------------------------------------------------------------------
__global__ __launch_bounds__(256) void xform_w(const float* __restrict__ w,
                                               bf16* __restrict__ wT) {
  int j = blockIdx.x * 256 + threadIdx.x;   // KSTEPS*256*8 threads
  int t8 = j & 7;              // 8-elem chunk within 64
  int c2 = (j >> 3) & 255;
  int kk = j >> 11;            // 0..675
  int q2 = kk & 3;
  int khkw = kk >> 2;
  int c1 = q2 * 64 + t8 * 8;
  const float* wp = w + ((size_t)c2 * C1c + c1) * (KS * KS) + khkw;
  bf16x8 v;
#pragma unroll
  for (int i = 0; i < 8; i++) v[i] = (bf16)wp[(size_t)i * KS * KS];
  *(bf16x8*)(wT + (size_t)j * 8) = v;
}

// ---------------------------------------------------------------------------
// Main: implicit-GEMM conv + BN + SiLU
//   tile: 128 c2 x 128 pixels, BK=64, 4 waves of 64x64 (4x4 mfma 16x16x32)
//   LDS rows are 64 elems (128 B); granule slot = g ^ (row&7)  (XOR swizzle,
//   realized by permuting per-lane *source* addresses of global_load_lds)
// ---------------------------------------------------------------------------
__device__ __forceinline__ void gload_lds16(const bf16* g, bf16* l) {
  __builtin_amdgcn_global_load_lds(
      (const __attribute__((address_space(1))) void*)(g),
      (__attribute__((address_space(3))) void*)(l),
      16, 0, 0);
}

__global__ __launch_bounds__(256, 3) void conv_mfma(
    const bf16* __restrict__ xT, const bf16* __restrict__ wT,
    const float* __restrict__ gamma, const float* __restrict__ beta,
    const float* __restrict__ rmean, const float* __restrict__ rvar,
    float* __restrict__ out) {
  __shared__ __attribute__((aligned(16))) bf16 As[128 * 64];
  __shared__ __attribute__((aligned(16))) bf16 Bs[128 * 64];
  __shared__ float sS[128];
  __shared__ float sB[128];

  const int tid = threadIdx.x;
  const int lane = tid & 63;
  const int wave = tid >> 6;           // 0..3
  const int wm = wave >> 1, wn = wave & 1;

  const int bid = blockIdx.x;
  const int c2t = bid & 1;             // 0..1
  const int pixt = bid >> 1;           // 0..391
  const int c2base = c2t * 128;
  const int pixbase = pixt * 128;

  // BN scale/bias for this block's 128 c2 rows
  if (tid < 128) {
    int row = c2base + tid;
    float s = gamma[row] * rsqrtf(rvar[row] + 1e-5f);
    sS[tid] = s;
    sB[tid] = beta[row] - rmean[row] * s;
  }

  // --- staging lane constants (XOR-swizzled source granule) ---
  const int lr = lane >> 3;            // row within an 8-row issue (0..7)
  const int ls = lane & 7;             // LDS slot (granule) within 128B row
  const int swz = (ls ^ lr) * 8;       // source granule elem offset (0..56)

  // A: wave covers c2 rows [wave*32, wave*32+32) in 4 issues of 8 rows
  int aOff[4];
#pragma unroll
  for (int i = 0; i < 4; i++)
    aOff[i] = (c2base + wave * 32 + i * 8 + lr) * 64 + swz;

  // B: wave covers pixels [wave*32, wave*32+32) in 4 issues of 8 pixels
  int pOffB[4];
#pragma unroll
  for (int i = 0; i < 4; i++) {
    int pix = pixbase + wave * 32 + i * 8 + lr;
    int n = pix / (HH * WW);
    int rr = pix - n * (HH * WW);
    int oh = rr / WW;
    int ow = rr - oh * WW;
    pOffB[i] = ((n * HP + oh) * HP + ow) * C1c + swz;
  }

  bf16* AsW = As + wave * 32 * 64;
  bf16* BsW = Bs + wave * 32 * 64;

  // fragment-read lane constants (apply the same XOR swizzle)
  const int mrow = lane & 15;
  const int kq = lane >> 4;            // k sub-chunk (8 elems)
  const int g0 = ((kq ^ (mrow & 7))) * 8;   // kc=0 granule elem offset
  // kc=1 offset is g0 ^ 32

  floatx4 acc[4][4];
#pragma unroll
  for (int mi = 0; mi < 4; mi++)
#pragma unroll
    for (int ni = 0; ni < 4; ni++) acc[mi][ni] = (floatx4){0.f, 0.f, 0.f, 0.f};

  const bf16* aStep = wT;
  for (int kh = 0; kh < KS; kh++) {
    for (int kw = 0; kw < KS; kw++) {
      const int spatial = (kh * HP + kw) * C1c;
#pragma unroll 1
      for (int q2 = 0; q2 < 4; q2++) {
        const int bO = spatial + q2 * 64;
        __syncthreads();   // previous iter's LDS reads done
#pragma unroll
        for (int i = 0; i < 4; i++)
          gload_lds16(aStep + aOff[i], AsW + i * 512);
#pragma unroll
        for (int i = 0; i < 4; i++)
          gload_lds16(xT + pOffB[i] + bO, BsW + i * 512);
        asm volatile("s_waitcnt vmcnt(0)" ::: "memory");
        __syncthreads();   // staged tiles visible

        bf16x8 af[4], bfr[4];
        // kc = 0
#pragma unroll
        for (int mi = 0; mi < 4; mi++)
          af[mi] = *(const bf16x8*)(As + (wm * 64 + mi * 16 + mrow) * 64 + g0);
#pragma unroll
        for (int ni = 0; ni < 4; ni++)
          bfr[ni] = *(const bf16x8*)(Bs + (wn * 64 + ni * 16 + mrow) * 64 + g0);
#pragma unroll
        for (int mi = 0; mi < 4; mi++)
#pragma unroll
          for (int ni = 0; ni < 4; ni++)
            acc[mi][ni] = __builtin_amdgcn_mfma_f32_16x16x32_bf16(
                af[mi], bfr[ni], acc[mi][ni], 0, 0, 0);
        // kc = 1
#pragma unroll
        for (int mi = 0; mi < 4; mi++)
          af[mi] = *(const bf16x8*)(As + (wm * 64 + mi * 16 + mrow) * 64 + (g0 ^ 32));
#pragma unroll
        for (int ni = 0; ni < 4; ni++)
          bfr[ni] = *(const bf16x8*)(Bs + (wn * 64 + ni * 16 + mrow) * 64 + (g0 ^ 32));
#pragma unroll
        for (int mi = 0; mi < 4; mi++)
#pragma unroll
          for (int ni = 0; ni < 4; ni++)
            acc[mi][ni] = __builtin_amdgcn_mfma_f32_16x16x32_bf16(
                af[mi], bfr[ni], acc[mi][ni], 0, 0, 0);

        aStep += 256 * 64;   // next K-step of wT (contiguous)
      }
    }
  }

  // --- epilogue: BN + SiLU, fp32 NCHW stores ---
  const int colL = lane & 15;
  const int quad = lane >> 4;
#pragma unroll
  for (int ni = 0; ni < 4; ni++) {
    int pix = pixbase + wn * 64 + ni * 16 + colL;
    int n = pix / (HH * WW);
    int rr = pix - n * (HH * WW);
    int oh = rr / WW;
    int ow = rr - oh * WW;
    size_t obase = (size_t)n * C2c * (HH * WW) + (size_t)oh * WW + ow;
#pragma unroll
    for (int mi = 0; mi < 4; mi++) {
      int row0 = wm * 64 + mi * 16 + quad * 4;
#pragma unroll
      for (int r = 0; r < 4; r++) {
        int rowl = row0 + r;
        float v = acc[mi][ni][r];
        v = v * sS[rowl] + sB[rowl];
        float o = v / (1.f + __expf(-v));
        out[obase + (size_t)(c2base + rowl) * (HH * WW)] = o;
      }
    }
  }
}

// ---------------------------------------------------------------------------
extern "C" void kernel_launch(void* const* d_in, const int* in_sizes, int n_in,
                              void* d_out, int out_size, void* d_ws, size_t ws_size,
                              hipStream_t stream) {
  const float* x     = (const float*)d_in[0];
  const float* w     = (const float*)d_in[1];
  const float* gamma = (const float*)d_in[2];
  const float* beta  = (const float*)d_in[3];
  const float* rmean = (const float*)d_in[4];
  const float* rvar  = (const float*)d_in[5];
  float* out = (float*)d_out;

  bf16* xT = (bf16*)d_ws;
  bf16* wT = xT + XT_ELEMS;

  if (ws_size < (XT_ELEMS + WT_ELEMS) * sizeof(bf16)) return;  // need ~57.3 MiB

  xform_x<<<(NBAT * HP * HP * 32) / 256, 256, 0, stream>>>(x, xT);
  xform_w<<<(KSTEPS * 256 * 8) / 256, 256, 0, stream>>>(w, wT);
  conv_mfma<<<2 * PIXTILES, 256, 0, stream>>>(xT, wT, gamma, beta, rmean, rvar, out);
}

// Round 3
// 1793.049 us; speedup vs baseline: 1.1816x; 1.0894x over previous
//
#include <hip/hip_runtime.h>
#include <hip/hip_bf16.h>

// Problem constants
#define C1c 256
#define C2c 256
#define NBAT 16
#define HH 56
#define WW 56
#define KS 13
#define PADc 6
#define HP 68                    // 56 + 2*6
#define NPIX (NBAT*HH*WW)        // 50176
#define PIXTILES (NPIX/128)      // 392
#define KSTEPS2 1352             // 169 * 8 steps of BK=32

typedef __bf16 bf16;
typedef bf16 bf16x8 __attribute__((ext_vector_type(8)));
typedef float floatx4 __attribute__((ext_vector_type(4)));

// Workspace layout (bf16):
//   xT : [NBAT*HP*HP][C1]          = 18,939,904 elems (37,879,808 B)
//   wT : [1352][256][32]           = 11,075,584 elems (22,151,168 B)
#define XT_ELEMS ((size_t)NBAT*HP*HP*C1c)
#define WT_ELEMS ((size_t)KSTEPS2*256*32)

// ---------------------------------------------------------------------------
// Pre-pass 1: x (N,C,H,W) fp32 -> xT [(n*68+hp)*68+wp][c1] bf16, zero-padded
// ---------------------------------------------------------------------------
__global__ __launch_bounds__(256) void xform_x(const float* __restrict__ x,
                                               bf16* __restrict__ xT) {
  int j = blockIdx.x * 256 + threadIdx.x;   // NBAT*HP*HP*32 threads
  int pos = j >> 5;
  int c1 = (j & 31) * 8;
  int n = pos / (HP * HP);
  int r = pos - n * (HP * HP);
  int hp = r / HP;
  int wp = r - hp * HP;
  int ih = hp - PADc, iw = wp - PADc;
  bf16x8 v;
  if (ih >= 0 && ih < HH && iw >= 0 && iw < WW) {
    const float* xp = x + ((size_t)(n * C1c + c1) * HH + ih) * WW + iw;
#pragma unroll
    for (int i = 0; i < 8; i++) v[i] = (bf16)xp[(size_t)i * HH * WW];
  } else {
#pragma unroll
    for (int i = 0; i < 8; i++) v[i] = (bf16)0.f;
  }
  *(bf16x8*)(xT + (size_t)pos * C1c + c1) = v;
}

// ---------------------------------------------------------------------------
// Pre-pass 2: w (C2,C1,13,13) fp32 -> wT [kk][c2][32] bf16
//   kk = khkw*8 + q,  c1 = q*32 + e
// ---------------------------------------------------------------------------
__global__ __launch_bounds__(256) void xform_w(const float* __restrict__ w,
                                               bf16* __restrict__ wT) {
  int j = blockIdx.x * 256 + threadIdx.x;   // KSTEPS2*256*4 threads
  int part = j & 3;
  int c2 = (j >> 2) & 255;
  int qk = j >> 10;            // khkw*8 + q, 0..1351
  int q = qk & 7;
  int khkw = qk >> 3;
  int c1 = q * 32 + part * 8;
  const float* wp = w + ((size_t)c2 * C1c + c1) * (KS * KS) + khkw;
  bf16x8 v;
#pragma unroll
  for (int i = 0; i < 8; i++) v[i] = (bf16)wp[(size_t)i * KS * KS];
  *(bf16x8*)(wT + (size_t)j * 8) = v;
}

// ---------------------------------------------------------------------------
// Main: implicit-GEMM conv + BN + SiLU, software-pipelined double buffer
//   tile: 128 c2 x 128 pixels, BK=32, 4 waves of 64x64 (4x4 mfma 16x16x32)
//   LDS rows 32 elems (64B, 4 granules); slot = g ^ ((row>>1)&3) XOR swizzle
//   realized by permuting per-lane *source* addresses of global_load_lds.
//   Pipeline: [wait own loads][barrier][issue prefetch k+1][compute k]
// ---------------------------------------------------------------------------
__device__ __forceinline__ void gload_lds16(const bf16* g, bf16* l) {
  __builtin_amdgcn_global_load_lds(
      (const __attribute__((address_space(1))) void*)(g),
      (__attribute__((address_space(3))) void*)(l),
      16, 0, 0);
}

__global__ __launch_bounds__(256, 4) void conv_mfma(
    const bf16* __restrict__ xT, const bf16* __restrict__ wT,
    const float* __restrict__ gamma, const float* __restrict__ beta,
    const float* __restrict__ rmean, const float* __restrict__ rvar,
    float* __restrict__ out) {
  __shared__ __attribute__((aligned(16))) bf16 As[2][128 * 32];
  __shared__ __attribute__((aligned(16))) bf16 Bs[2][128 * 32];
  __shared__ float sS[128];
  __shared__ float sB[128];

  const int tid = threadIdx.x;
  const int lane = tid & 63;
  const int wave = tid >> 6;           // 0..3
  const int wm = wave >> 1, wn = wave & 1;

  const int bid = blockIdx.x;
  const int c2t = bid & 1;             // 0..1
  const int pixt = bid >> 1;           // 0..391
  const int c2base = c2t * 128;
  const int pixbase = pixt * 128;

  // BN scale/bias for this block's 128 c2 rows
  if (tid < 128) {
    int row = c2base + tid;
    float s = gamma[row] * rsqrtf(rvar[row] + 1e-5f);
    sS[tid] = s;
    sB[tid] = beta[row] - rmean[row] * s;
  }

  // --- staging lane constants (XOR-swizzled source granule) ---
  const int part = lane & 3;                 // LDS slot within 64B row
  const int rsub = lane >> 2;                // row within a 16-row issue
  const int srcg = (part ^ ((rsub >> 1) & 3)) * 8;  // source granule elems

  // A: wave covers c2 rows [wave*32, wave*32+32) in 2 issues of 16 rows
  int aOff0 = (c2base + wave * 32 + rsub) * 32 + srcg;
  int aOff1 = (c2base + wave * 32 + 16 + rsub) * 32 + srcg;

  // B: wave covers pixels [wave*32, wave*32+32) in 2 issues of 16 pixels
  int pOff0, pOff1;
#pragma unroll
  for (int i = 0; i < 2; i++) {
    int pix = pixbase + wave * 32 + i * 16 + rsub;
    int n = pix / (HH * WW);
    int rr = pix - n * (HH * WW);
    int oh = rr / WW;
    int ow = rr - oh * WW;
    int po = ((n * HP + oh) * HP + ow) * C1c + srcg;
    if (i == 0) pOff0 = po; else pOff1 = po;
  }

  // fragment-read lane constants (same XOR swizzle; constant per lane)
  const int mrow = lane & 15;
  const int kq = lane >> 4;                        // source k granule
  const int g0 = (kq ^ ((mrow >> 1) & 3)) * 8;     // swizzled LDS offset

  floatx4 acc[4][4];
#pragma unroll
  for (int mi = 0; mi < 4; mi++)
#pragma unroll
    for (int ni = 0; ni < 4; ni++) acc[mi][ni] = (floatx4){0.f, 0.f, 0.f, 0.f};

  const int ldsW = wave * 1024;   // wave's 32 rows * 32 elems

  // prologue: stage step 0 into buffer 0 (step 0: bO = 0, aS = wT)
  gload_lds16(wT + aOff0, &As[0][ldsW]);
  gload_lds16(wT + aOff1, &As[0][ldsW + 512]);
  gload_lds16(xT + pOff0, &Bs[0][ldsW]);
  gload_lds16(xT + pOff1, &Bs[0][ldsW + 512]);

  auto do_step = [&](int kk, const bf16* Ac, const bf16* Bc,
                     bf16* An, bf16* Bn) {
    // next-step source offsets
    int kn = kk + 1;
    if (kn == KSTEPS2) kn = 0;        // harmless dummy prefetch on last iter
    int q = kn & 7;
    int t = kn >> 3;
    int kwn = t % 13;
    int khn = t / 13;
    int bO = (khn * HP + kwn) * C1c + q * 32;
    const bf16* aS = wT + (size_t)kn * 8192;

    asm volatile("s_waitcnt vmcnt(0)" ::: "memory");  // own prefetch landed
    __syncthreads();                                  // visible to all waves

    // issue prefetch for step kk+1 into the other buffer — stays in flight
    // across the whole compute phase below
    gload_lds16(aS + aOff0, An + ldsW);
    gload_lds16(aS + aOff1, An + ldsW + 512);
    gload_lds16(xT + pOff0 + bO, Bn + ldsW);
    gload_lds16(xT + pOff1 + bO, Bn + ldsW + 512);

    // compute step kk from current buffer
    bf16x8 af[4], bfr[4];
#pragma unroll
    for (int mi = 0; mi < 4; mi++)
      af[mi] = *(const bf16x8*)(Ac + (wm * 64 + mi * 16 + mrow) * 32 + g0);
#pragma unroll
    for (int ni = 0; ni < 4; ni++)
      bfr[ni] = *(const bf16x8*)(Bc + (wn * 64 + ni * 16 + mrow) * 32 + g0);
#pragma unroll
    for (int mi = 0; mi < 4; mi++)
#pragma unroll
      for (int ni = 0; ni < 4; ni++)
        acc[mi][ni] = __builtin_amdgcn_mfma_f32_16x16x32_bf16(
            af[mi], bfr[ni], acc[mi][ni], 0, 0, 0);
  };

#pragma unroll 1
  for (int kk = 0; kk < KSTEPS2; kk += 2) {
    do_step(kk,     As[0], Bs[0], As[1], Bs[1]);
    do_step(kk + 1, As[1], Bs[1], As[0], Bs[0]);
  }

  // --- epilogue: BN + SiLU, fp32 NCHW stores ---
  const int colL = lane & 15;
  const int quad = lane >> 4;
#pragma unroll
  for (int ni = 0; ni < 4; ni++) {
    int pix = pixbase + wn * 64 + ni * 16 + colL;
    int n = pix / (HH * WW);
    int rr = pix - n * (HH * WW);
    int oh = rr / WW;
    int ow = rr - oh * WW;
    size_t obase = (size_t)n * C2c * (HH * WW) + (size_t)oh * WW + ow;
#pragma unroll
    for (int mi = 0; mi < 4; mi++) {
      int row0 = wm * 64 + mi * 16 + quad * 4;
#pragma unroll
      for (int r = 0; r < 4; r++) {
        int rowl = row0 + r;
        float v = acc[mi][ni][r];
        v = v * sS[rowl] + sB[rowl];
        float o = v / (1.f + __expf(-v));
        out[obase + (size_t)(c2base + rowl) * (HH * WW)] = o;
      }
    }
  }
}

// ---------------------------------------------------------------------------
extern "C" void kernel_launch(void* const* d_in, const int* in_sizes, int n_in,
                              void* d_out, int out_size, void* d_ws, size_t ws_size,
                              hipStream_t stream) {
  const float* x     = (const float*)d_in[0];
  const float* w     = (const float*)d_in[1];
  const float* gamma = (const float*)d_in[2];
  const float* beta  = (const float*)d_in[3];
  const float* rmean = (const float*)d_in[4];
  const float* rvar  = (const float*)d_in[5];
  float* out = (float*)d_out;

  bf16* xT = (bf16*)d_ws;
  bf16* wT = xT + XT_ELEMS;

  if (ws_size < (XT_ELEMS + WT_ELEMS) * sizeof(bf16)) return;  // need ~57.3 MiB

  xform_x<<<(NBAT * HP * HP * 32) / 256, 256, 0, stream>>>(x, xT);
  xform_w<<<(KSTEPS2 * 256 * 4) / 256, 256, 0, stream>>>(w, wT);
  conv_mfma<<<2 * PIXTILES, 256, 0, stream>>>(xT, wT, gamma, beta, rmean, rvar, out);
}

// Round 4
// 1650.942 us; speedup vs baseline: 1.2833x; 1.0861x over previous
//
#include <hip/hip_runtime.h>
#include <hip/hip_bf16.h>

// Problem constants
#define C1c 256
#define C2c 256
#define NBAT 16
#define HH 56
#define WW 56
#define KS 13
#define PADc 6
#define HP 68                    // 56 + 2*6
#define NPIX (NBAT*HH*WW)        // 50176
#define PIXTILES (NPIX/128)      // 392
#define KSTEPS2 1352             // 169 * 8 steps of BK=32, order (kh, q, kw)

typedef __bf16 bf16;
typedef bf16 bf16x8 __attribute__((ext_vector_type(8)));
typedef float floatx4 __attribute__((ext_vector_type(4)));

// Workspace layout (bf16):
//   xT : [NBAT*HP*HP][C1]          = 18,939,904 elems (37,879,808 B)
//   wT : [1352][256][32]           = 11,075,584 elems (22,151,168 B)
#define XT_ELEMS ((size_t)NBAT*HP*HP*C1c)
#define WT_ELEMS ((size_t)KSTEPS2*256*32)

// ---------------------------------------------------------------------------
// Pre-pass 1: x (N,C,H,W) fp32 -> xT [(n*68+hp)*68+wp][c1] bf16, zero-padded
// ---------------------------------------------------------------------------
__global__ __launch_bounds__(256) void xform_x(const float* __restrict__ x,
                                               bf16* __restrict__ xT) {
  int j = blockIdx.x * 256 + threadIdx.x;   // NBAT*HP*HP*32 threads
  int pos = j >> 5;
  int c1 = (j & 31) * 8;
  int n = pos / (HP * HP);
  int r = pos - n * (HP * HP);
  int hp = r / HP;
  int wp = r - hp * HP;
  int ih = hp - PADc, iw = wp - PADc;
  bf16x8 v;
  if (ih >= 0 && ih < HH && iw >= 0 && iw < WW) {
    const float* xp = x + ((size_t)(n * C1c + c1) * HH + ih) * WW + iw;
#pragma unroll
    for (int i = 0; i < 8; i++) v[i] = (bf16)xp[(size_t)i * HH * WW];
  } else {
#pragma unroll
    for (int i = 0; i < 8; i++) v[i] = (bf16)0.f;
  }
  *(bf16x8*)(xT + (size_t)pos * C1c + c1) = v;
}

// ---------------------------------------------------------------------------
// Pre-pass 2: w (C2,C1,13,13) fp32 -> wT [kk][c2][32] bf16
//   kk = (kh*8 + q)*13 + kw,  c1 = q*32 + e   (kw innermost for xT L2 reuse)
// ---------------------------------------------------------------------------
__global__ __launch_bounds__(256) void xform_w(const float* __restrict__ w,
                                               bf16* __restrict__ wT) {
  int j = blockIdx.x * 256 + threadIdx.x;   // KSTEPS2*256*4 threads
  int part = j & 3;
  int c2 = (j >> 2) & 255;
  int kk = j >> 10;            // 0..1351
  int kw = kk % 13;
  int t = kk / 13;
  int q = t & 7;
  int kh = t >> 3;
  int c1 = q * 32 + part * 8;
  const float* wp = w + ((size_t)c2 * C1c + c1) * (KS * KS) + kh * KS + kw;
  bf16x8 v;
#pragma unroll
  for (int i = 0; i < 8; i++) v[i] = (bf16)wp[(size_t)i * KS * KS];
  *(bf16x8*)(wT + (size_t)j * 8) = v;
}

// ---------------------------------------------------------------------------
// Main: implicit-GEMM conv + BN + SiLU, 3-deep software pipeline
//   tile: 128 c2 x 128 pixels, BK=32, 4 waves of 64x64 (4x4 mfma 16x16x32)
//   Pipeline: [vmcnt(4): step-k loads done][raw s_barrier][ds_read frags k]
//             [issue prefetch k+2][MFMA k] — prefetch has ~2 steps to land.
//   XOR swizzle slot = part ^ ((row>>1)&3), applied on *source* addresses.
// ---------------------------------------------------------------------------
__device__ __forceinline__ void gload_lds16(const bf16* g, bf16* l) {
  __builtin_amdgcn_global_load_lds(
      (const __attribute__((address_space(1))) void*)(g),
      (__attribute__((address_space(3))) void*)(l),
      16, 0, 0);
}

__global__ __launch_bounds__(256, 3) void conv_mfma(
    const bf16* __restrict__ xT, const bf16* __restrict__ wT,
    const float* __restrict__ gamma, const float* __restrict__ beta,
    const float* __restrict__ rmean, const float* __restrict__ rvar,
    float* __restrict__ out) {
  __shared__ __attribute__((aligned(16))) bf16 As[3][128 * 32];
  __shared__ __attribute__((aligned(16))) bf16 Bs[3][128 * 32];
  __shared__ float sS[128];
  __shared__ float sB[128];

  const int tid = threadIdx.x;
  const int lane = tid & 63;
  const int wave = tid >> 6;           // 0..3
  const int wm = wave >> 1, wn = wave & 1;

  const int bid = blockIdx.x;
  const int c2t = bid & 1;             // 0..1
  const int pixt = bid >> 1;           // 0..391
  const int c2base = c2t * 128;
  const int pixbase = pixt * 128;

  // BN scale/bias for this block's 128 c2 rows
  if (tid < 128) {
    int row = c2base + tid;
    float s = gamma[row] * rsqrtf(rvar[row] + 1e-5f);
    sS[tid] = s;
    sB[tid] = beta[row] - rmean[row] * s;
  }
  __syncthreads();

  // --- staging lane constants (XOR-swizzled source granule) ---
  const int part = lane & 3;                 // LDS slot within 64B row
  const int rsub = lane >> 2;                // row within a 16-row issue
  const int srcg = (part ^ ((rsub >> 1) & 3)) * 8;  // source granule elems

  // A: wave covers c2 rows [wave*32, wave*32+32) in 2 issues of 16 rows
  const int aOff0 = (c2base + wave * 32 + rsub) * 32 + srcg;
  const int aOff1 = (c2base + wave * 32 + 16 + rsub) * 32 + srcg;

  // B: wave covers pixels [wave*32, wave*32+32) in 2 issues of 16 pixels
  int pOff0, pOff1;
#pragma unroll
  for (int i = 0; i < 2; i++) {
    int pix = pixbase + wave * 32 + i * 16 + rsub;
    int n = pix / (HH * WW);
    int rr = pix - n * (HH * WW);
    int oh = rr / WW;
    int ow = rr - oh * WW;
    int po = ((n * HP + oh) * HP + ow) * C1c + srcg;
    if (i == 0) pOff0 = po; else pOff1 = po;
  }

  // fragment-read lane constants (same XOR swizzle; constant per lane)
  const int mrow = lane & 15;
  const int kq = lane >> 4;                        // source k granule
  const int g0 = (kq ^ ((mrow >> 1) & 3)) * 8;     // swizzled LDS offset

  floatx4 acc[4][4];
#pragma unroll
  for (int mi = 0; mi < 4; mi++)
#pragma unroll
    for (int ni = 0; ni < 4; ni++) acc[mi][ni] = (floatx4){0.f, 0.f, 0.f, 0.f};

  const int ldsW = wave * 1024;   // wave's 32 rows * 32 elems

  // prologue: stage step 0 -> buf0, step 1 -> buf1
  // step kk: kw = kk%13, q = (kk/13)&7, kh = kk/104
  //   bO = (kh*HP + kw)*C1c + q*32 ; wT slab = kk*8192
  gload_lds16(wT + aOff0, &As[0][ldsW]);
  gload_lds16(wT + aOff1, &As[0][ldsW + 512]);
  gload_lds16(xT + pOff0, &Bs[0][ldsW]);
  gload_lds16(xT + pOff1, &Bs[0][ldsW + 512]);
  gload_lds16(wT + 8192 + aOff0, &As[1][ldsW]);
  gload_lds16(wT + 8192 + aOff1, &As[1][ldsW + 512]);
  gload_lds16(xT + pOff0 + C1c, &Bs[1][ldsW]);    // step1: kw=1
  gload_lds16(xT + pOff1 + C1c, &Bs[1][ldsW + 512]);

  // rolling prefetch state for step kn = kk + 2
  int kwn = 2, qn = 0, khn = 0;
  const bf16* aPre = wT + 2 * 8192;

  auto do_step = [&](const bf16* Ac, const bf16* Bc, bf16* An, bf16* Bn) {
    asm volatile("s_waitcnt vmcnt(4)" ::: "memory");  // step-k loads landed
    __builtin_amdgcn_s_barrier();                     // visible to all waves

    // fragment loads for step k (before prefetch issue, so any
    // compiler-inserted hazard wait covers only 1-step-old loads)
    bf16x8 af[4], bfr[4];
#pragma unroll
    for (int mi = 0; mi < 4; mi++)
      af[mi] = *(const bf16x8*)(Ac + (wm * 64 + mi * 16 + mrow) * 32 + g0);
#pragma unroll
    for (int ni = 0; ni < 4; ni++)
      bfr[ni] = *(const bf16x8*)(Bc + (wn * 64 + ni * 16 + mrow) * 32 + g0);

    // issue prefetch for step k+2 — in flight across ~2 full steps
    int bOn = (khn * HP + kwn) * C1c + qn * 32;
    gload_lds16(aPre + aOff0, An + ldsW);
    gload_lds16(aPre + aOff1, An + ldsW + 512);
    gload_lds16(xT + pOff0 + bOn, Bn + ldsW);
    gload_lds16(xT + pOff1 + bOn, Bn + ldsW + 512);

    // advance prefetch counters (kw innermost)
    kwn++; aPre += 8192;
    if (kwn == 13) {
      kwn = 0; qn++;
      if (qn == 8) {
        qn = 0; khn++;
        if (khn == 13) { khn = 0; aPre = wT; }  // tail dummies wrap to step 0
      }
    }

#pragma unroll
    for (int mi = 0; mi < 4; mi++)
#pragma unroll
      for (int ni = 0; ni < 4; ni++)
        acc[mi][ni] = __builtin_amdgcn_mfma_f32_16x16x32_bf16(
            af[mi], bfr[ni], acc[mi][ni], 0, 0, 0);
  };

#pragma unroll 1
  for (int kk = 0; kk < KSTEPS2 - 2; kk += 3) {
    do_step(As[0], Bs[0], As[2], Bs[2]);
    do_step(As[1], Bs[1], As[0], Bs[0]);
    do_step(As[2], Bs[2], As[1], Bs[1]);
  }
  // tail: steps 1350 (buf0), 1351 (buf1); prefetches are harmless dummies
  do_step(As[0], Bs[0], As[2], Bs[2]);
  do_step(As[1], Bs[1], As[0], Bs[0]);

  // --- epilogue: BN + SiLU, fp32 NCHW stores ---
  const int colL = lane & 15;
  const int quad = lane >> 4;
#pragma unroll
  for (int ni = 0; ni < 4; ni++) {
    int pix = pixbase + wn * 64 + ni * 16 + colL;
    int n = pix / (HH * WW);
    int rr = pix - n * (HH * WW);
    int oh = rr / WW;
    int ow = rr - oh * WW;
    size_t obase = (size_t)n * C2c * (HH * WW) + (size_t)oh * WW + ow;
#pragma unroll
    for (int mi = 0; mi < 4; mi++) {
      int row0 = wm * 64 + mi * 16 + quad * 4;
#pragma unroll
      for (int r = 0; r < 4; r++) {
        int rowl = row0 + r;
        float v = acc[mi][ni][r];
        v = v * sS[rowl] + sB[rowl];
        float o = v / (1.f + __expf(-v));
        out[obase + (size_t)(c2base + rowl) * (HH * WW)] = o;
      }
    }
  }
}

// ---------------------------------------------------------------------------
extern "C" void kernel_launch(void* const* d_in, const int* in_sizes, int n_in,
                              void* d_out, int out_size, void* d_ws, size_t ws_size,
                              hipStream_t stream) {
  const float* x     = (const float*)d_in[0];
  const float* w     = (const float*)d_in[1];
  const float* gamma = (const float*)d_in[2];
  const float* beta  = (const float*)d_in[3];
  const float* rmean = (const float*)d_in[4];
  const float* rvar  = (const float*)d_in[5];
  float* out = (float*)d_out;

  bf16* xT = (bf16*)d_ws;
  bf16* wT = xT + XT_ELEMS;

  if (ws_size < (XT_ELEMS + WT_ELEMS) * sizeof(bf16)) return;  // need ~57.3 MiB

  xform_x<<<(NBAT * HP * HP * 32) / 256, 256, 0, stream>>>(x, xT);
  xform_w<<<(KSTEPS2 * 256 * 4) / 256, 256, 0, stream>>>(w, wT);
  conv_mfma<<<2 * PIXTILES, 256, 0, stream>>>(xT, wT, gamma, beta, rmean, rvar, out);
}